// Round 2
// 269.637 us; speedup vs baseline: 1.2261x; 1.2261x over previous
//
#include <hip/hip_runtime.h>

// MPNN sparse on MI355X (fp32 I/O, bf16 MFMA compute).
// R11 (resubmit — R11 bench was lost to GPUAcquisitionTimeout, no data).
// Single-atomic-pass scatter + coalesced epilogues.
//   R10 post-mortem: pq_scatter at 84us with MfmaUtil 3.5% / VALU 6.7% / HBM 23%
//   -> memory-side-op bound. Device-scope atomics bypass the non-coherent
//   per-XCD L2s (WRITE_SIZE 142MB vs ~55MB expected = atomic/4B-store RMW
//   amplification), and the pipeline paid the 800K-atomic wall TWICE
//   (pack_hist histogram + scatter rank) plus two scan kernels.
// Fixes:
//   * Fixed-capacity buckets (ECAP=96 >> Poisson(16) tail): the rank-returning
//     atomicAdd IS the histogram -> pack_hist's atomic pass, scan1, scan2,
//     offA/bsum/bsumEx all deleted. Guaranteed-correct overflow list kept.
//   * es stores ushort source only (t implied by bucket) -> half footprint.
//   * GEMM/scatter blocks interleaved (every 5th block GEMM) so atomic
//     latency hides under MFMA.
//   * PQ epilogue: wave-private padded LDS staging -> dwordx4 coalesced row
//     stores (was 64 scattered 4B stores/lane -> ~16 transactions/instr).
//   * node2 out: same LDS-staged coalesced f32 store.
// Pipeline (4 kernels): prep+pack -> pq_gemm|scatter -> hsum -> node2.

#define N_NODES 50000
#define E_EDGES 800000
#define DF   144
#define DIN  128
#define DDEG 16
#define DMSG 128
#define SA_LD 296     // 288 + 8 pad (shorts)
#define SH_LD 264     // 256 + 8 pad (shorts)
#define PQ_LD 512     // P'(256) | Q(256) per node, bf16
#define KA_LD 168     // 160 + 8 pad (pq A staging)
#define EP_W  68      // epilogue LDS stride in words (64 data + 4 pad)
#define ECAP 96       // fixed bucket capacity per target
#define OVER_CAP 4096
#define PQ_BLOCKS 782     // ceil(50000/64)
#define HIST_BLOCKS 3125  // 800000/256
#define PACK_THREADS 27648
#define PREP_BLOCKS 3516  // ceil(50000*18/256)
#define PACK_BLOCKS 108   // 27648/256

typedef __attribute__((ext_vector_type(8))) short short8;
typedef __attribute__((ext_vector_type(4))) float floatx4;
typedef __attribute__((ext_vector_type(4))) unsigned int uintx4;

__device__ __forceinline__ unsigned int fasu(float f){
  union { float f; unsigned int u; } v; v.f = f; return v.u;
}
__device__ __forceinline__ float uasf(unsigned int u){
  union { unsigned int u; float f; } v; v.u = u; return v.f;
}
__device__ __forceinline__ short f2bf(float f){           // RNE
  unsigned int i = fasu(f);
  unsigned int r = i + 0x7fffu + ((i >> 16) & 1u);
  return (short)(r >> 16);
}
__device__ __forceinline__ unsigned int pk_trunc(float lo, float hi){
  return __builtin_amdgcn_perm(fasu(hi), fasu(lo), 0x07060302u);
}

// ---- sentinel: ws too small -> out = 2.0 (diagnostic) ----
__global__ void sentinel_kernel(float* __restrict__ out){
  int i = blockIdx.x * blockDim.x + threadIdx.x;
  if (i < N_NODES * DMSG){ out[i] = 2.0f; }
}

// ---- pack helpers ----
__device__ __forceinline__ void pack_w_dev(const float* __restrict__ W,
                                           short* __restrict__ Wp,
                                           int Ksrc, int nT, int t){
  int lane = t & 63;
  int rest = t >> 6;
  int nt = rest % nT;
  int chunk = rest / nT;
  int Ncols = nT * 16;
  int n = nt * 16 + (lane & 15);
  int kbase = chunk * 32 + (lane >> 4) * 8;
  short8 v;
  for (int j = 0; j < 8; ++j){
    int k = kbase + j;
    short o = 0;
    if (k < Ksrc){ o = f2bf(W[(size_t)k * Ncols + n]); }
    v[j] = o;
  }
  *(short8*)(Wp + (size_t)t * 8) = v;
}
__device__ __forceinline__ void pack_w1pq_dev(const float* __restrict__ W1,
                                              short* __restrict__ Wp, int t){
  int lane = t & 63;
  int rest = t >> 6;
  int nt = rest % 32;
  int chunk = rest / 32;
  int col = nt * 16 + (lane & 15);
  int kbase = chunk * 32 + (lane >> 4) * 8;
  short8 v;
  for (int j = 0; j < 8; ++j){
    int k = kbase + j;
    short o = 0;
    if (k < 144){
      float w = (col < 256) ? W1[(size_t)k * 256 + col]
                            : W1[(size_t)(144 + k) * 256 + (col - 256)];
      o = f2bf(w);
    }
    v[j] = o;
  }
  *(short8*)(Wp + (size_t)t * 8) = v;
}

// ---- kernel 1: prep (cnt=0, nOver=0, h=bf16[x|deg]) + weight pack ----
__global__ void prep_pack_kernel(const float* __restrict__ x, const float* __restrict__ deg,
                                 const float* __restrict__ mW1, const float* __restrict__ mW2,
                                 const float* __restrict__ uW1, const float* __restrict__ uW2,
                                 short* __restrict__ w1pq, short* __restrict__ w2m,
                                 short* __restrict__ w1u, short* __restrict__ w2u,
                                 int* __restrict__ cnt, int* __restrict__ nOver,
                                 short* __restrict__ h){
  if (blockIdx.x >= PREP_BLOCKS){
    int t2 = (blockIdx.x - PREP_BLOCKS) * 256 + threadIdx.x;
    if (t2 < 4096){ pack_w_dev(mW2, w2m, 256, 8, t2); }
    else if (t2 < 13312){ pack_w_dev(uW1, w1u, 272, 16, t2 - 4096); }
    else if (t2 < 17408){ pack_w_dev(uW2, w2u, 256, 8, t2 - 13312); }
    else { pack_w1pq_dev(mW1, w1pq, t2 - 17408); }
    return;
  }
  int i = blockIdx.x * 256 + threadIdx.x;
  if (i < N_NODES){ cnt[i] = 0; }
  if (i == 0){ *nOver = 0; }
  if (i < N_NODES * 18){
    int n = i / 18;
    int j = i - n * 18;
    const float* src;
    if (j < 16){ src = x + (size_t)n * DIN + (size_t)j * 8; }
    else       { src = deg + (size_t)n * DDEG + (size_t)(j - 16) * 8; }
    short8 v;
    for (int t = 0; t < 8; ++t){ v[t] = f2bf(src[t]); }
    *(short8*)(h + (size_t)n * DF + (size_t)j * 8) = v;
  }
}

// ---- kernel 2: fused PQ GEMM + single-pass edge scatter (interleaved) ----
__launch_bounds__(256, 2)
__global__ void pq_scatter_kernel(const short* __restrict__ h, const short* __restrict__ w1pq,
                                  const float* __restrict__ b1, short* __restrict__ PQ,
                                  const int* __restrict__ ei, int* __restrict__ cnt,
                                  int* __restrict__ nOver, unsigned int* __restrict__ over,
                                  unsigned short* __restrict__ es){
  __shared__ __align__(16) unsigned int sE[4 * 32 * EP_W];   // 34816 B, unioned with sA

  const int g = blockIdx.x;
  const bool isG = ((g % 5) == 0) && ((g / 5) < PQ_BLOCKS);
  if (!isG){
    // scatter block: one atomic per edge = rank AND histogram
    int nb = (g / 5) + 1; if (nb > PQ_BLOCKS) nb = PQ_BLOCKS;
    int e = (g - nb) * 256 + threadIdx.x;
    if (e < E_EDGES){
      int s = ei[e];
      int t = ei[E_EDGES + e];
      if ((unsigned)s >= (unsigned)N_NODES) s = 0;
      if ((unsigned)t >= (unsigned)N_NODES) t = 0;
      int r = atomicAdd(cnt + t, 1);
      if (r < ECAP){
        es[(size_t)t * ECAP + r] = (unsigned short)s;
      } else {
        int p = atomicAdd(nOver, 1);
        if (p < OVER_CAP){ over[p] = ((unsigned int)t << 16) | (unsigned int)s; }
      }
    }
    return;
  }

  const int tid  = threadIdx.x;
  const int lane = tid & 63;
  const int wave = tid >> 6;
  const int q    = lane >> 4;
  const int lr   = lane & 15;
  const int n0   = (g / 5) * 64;
  short* sA = (short*)sE;

  {
    int row = tid >> 2;
    int quarter = tid & 3;
    int n = n0 + row;
    if (n >= N_NODES) n = 0;
    const short* hp = h + (size_t)n * DF;
    short* dstp = sA + row * KA_LD + quarter * 40;
    #pragma unroll
    for (int c5 = 0; c5 < 5; ++c5){
      int col = quarter * 40 + c5 * 8;
      short8 v;
      if (col < DF){
        v = *(const short8*)(hp + col);
      } else {
        for (int j = 0; j < 8; ++j){ v[j] = 0; }
      }
      *(short8*)(dstp + c5 * 8) = v;
    }
  }
  __syncthreads();

  floatx4 acc[4][8];
  #pragma unroll
  for (int it = 0; it < 4; ++it){
    #pragma unroll
    for (int jt = 0; jt < 8; ++jt){
      #pragma unroll
      for (int r = 0; r < 4; ++r){ acc[it][jt][r] = 0.0f; }
    }
  }

  for (int kc = 0; kc < 5; ++kc){
    short8 aF[4];
    #pragma unroll
    for (int it = 0; it < 4; ++it){
      aF[it] = *(const short8*)(sA + (it * 16 + lr) * KA_LD + kc * 32 + q * 8);
    }
    #pragma unroll
    for (int jt = 0; jt < 8; ++jt){
      short8 bF = *(const short8*)(w1pq + ((size_t)(kc * 32 + wave * 8 + jt) * 64 + lane) * 8);
      #pragma unroll
      for (int it = 0; it < 4; ++it){
        acc[it][jt] = __builtin_amdgcn_mfma_f32_16x16x32_bf16(aF[it], bF, acc[it][jt], 0, 0, 0);
      }
    }
  }
  __syncthreads();   // all waves done reading sA before epilogue overwrites it

  // Epilogue: wave-private LDS staging (2 rounds x 32 rows), coalesced PQ rows.
  const int waveBase = wave * (32 * EP_W);
  #pragma unroll
  for (int rnd = 0; rnd < 2; ++rnd){
    #pragma unroll
    for (int il = 0; il < 2; ++il){
      const int it = rnd * 2 + il;
      #pragma unroll
      for (int jt = 0; jt < 8; ++jt){
        int col  = (wave * 8 + jt) * 16 + lr;
        float bb = (col < 256) ? b1[col] : 0.0f;
        floatx4 a = acc[it][jt];
        unsigned int pk01 = pk_trunc(a[0] + bb, a[1] + bb);
        unsigned int pk23 = pk_trunc(a[2] + bb, a[3] + bb);
        unsigned int send = (lr & 1) ? pk01 : pk23;
        unsigned int t = (unsigned int)__shfl_xor((int)send, 1, 64);
        int lrow;
        unsigned int w0, w1;
        if ((lr & 1) == 0){
          lrow = il * 16 + q * 4;
          w0 = (pk01 & 0xffffu) | ((t & 0xffffu) << 16);
          w1 = (pk01 >> 16)     | (t & 0xffff0000u);
        } else {
          lrow = il * 16 + q * 4 + 2;
          w0 = (t & 0xffffu) | ((pk23 & 0xffffu) << 16);
          w1 = (t >> 16)     | (pk23 & 0xffff0000u);
        }
        int wv = jt * 8 + (lr >> 1);
        sE[waveBase + lrow * EP_W + wv] = w0;
        sE[waveBase + (lrow + 1) * EP_W + wv] = w1;
      }
    }
    #pragma unroll
    for (int rr = 0; rr < 8; ++rr){
      int lrow = rr * 4 + (lane >> 4);
      int grow = n0 + rnd * 32 + lrow;
      uintx4 v = *(const uintx4*)(sE + waveBase + lrow * EP_W + (lane & 15) * 4);
      if (grow < N_NODES){
        *(uintx4*)((unsigned int*)PQ + (size_t)grow * 256 + wave * 64 + (lane & 15) * 4) = v;
      }
    }
  }
}

// ---- kernel 3: hsum — one wave per target; plain coalesced bf16 store ----
__launch_bounds__(256, 8)
__global__ void hsum_kernel(const short* __restrict__ PQ, const unsigned short* __restrict__ es,
                            const int* __restrict__ cnt, const unsigned int* __restrict__ over,
                            const int* __restrict__ nOver, short* __restrict__ HsumB){
  const int lane = threadIdx.x & 63;
  const int wave = threadIdx.x >> 6;
  const int t = blockIdx.x * 4 + wave;          // grid covers exactly N_NODES
  const unsigned int* PQu = (const unsigned int*)PQ;

  float a0 = 0.0f, a1 = 0.0f, a2 = 0.0f, a3 = 0.0f;
  int d = cnt[t];
  if (d > 0){
    int dc = d < ECAP ? d : ECAP;
    int start = t * ECAP;
    uint2 pv = *(const uint2*)(PQu + (size_t)t * 256 + lane * 2);
    float Pf0 = uasf(pv.x << 16), Pf1 = uasf(pv.x & 0xffff0000u);
    float Pf2 = uasf(pv.y << 16), Pf3 = uasf(pv.y & 0xffff0000u);
    for (int base = 0; base < dc; base += 64){
      int m = dc - base;
      if (m > 64) m = 64;
      unsigned int el = (lane < m) ? (unsigned int)es[start + base + lane] : 0u;
      unsigned int s0 = (unsigned int)__shfl((int)el, 0, 64);
      uint2 qv = *(const uint2*)(PQu + (size_t)s0 * 256 + 128 + lane * 2);
      for (int j = 0; j < m; ++j){
        uint2 qn;
        if (j + 1 < m){
          unsigned int s1 = (unsigned int)__shfl((int)el, j + 1, 64);
          qn = *(const uint2*)(PQu + (size_t)s1 * 256 + 128 + lane * 2);
        }
        float v;
        v = Pf0 + uasf(qv.x << 16);          a0 += v > 0.0f ? v : 0.0f;
        v = Pf1 + uasf(qv.x & 0xffff0000u);  a1 += v > 0.0f ? v : 0.0f;
        v = Pf2 + uasf(qv.y << 16);          a2 += v > 0.0f ? v : 0.0f;
        v = Pf3 + uasf(qv.y & 0xffff0000u);  a3 += v > 0.0f ? v : 0.0f;
        qv = qn;
      }
    }
    if (d > ECAP){   // astronomically rare; guaranteed-correct replay
      int no = *nOver;
      if (no > OVER_CAP) no = OVER_CAP;
      for (int p = 0; p < no; ++p){
        unsigned int w = over[p];
        if ((int)(w >> 16) == t){
          unsigned int s1 = w & 0xffffu;
          uint2 qv = *(const uint2*)(PQu + (size_t)s1 * 256 + 128 + lane * 2);
          float v;
          v = Pf0 + uasf(qv.x << 16);          a0 += v > 0.0f ? v : 0.0f;
          v = Pf1 + uasf(qv.x & 0xffff0000u);  a1 += v > 0.0f ? v : 0.0f;
          v = Pf2 + uasf(qv.y << 16);          a2 += v > 0.0f ? v : 0.0f;
          v = Pf3 + uasf(qv.y & 0xffff0000u);  a3 += v > 0.0f ? v : 0.0f;
        }
      }
    }
  }
  uint2 o;
  o.x = pk_trunc(a0, a1);
  o.y = pk_trunc(a2, a3);
  *(uint2*)((unsigned int*)HsumB + (size_t)t * 128 + lane * 2) = o;
}

// ---- kernel 4: node2 — agg = HsumB@W2m + cnt*b2m fused in front of node MLP ----
__launch_bounds__(256, 4)
__global__ void node2_kernel(const short* __restrict__ h, const short* __restrict__ HsumB,
                             const int* __restrict__ cnt,
                             const short* __restrict__ w2m, const float* __restrict__ b2m,
                             const short* __restrict__ w1u, const float* __restrict__ b1u,
                             const short* __restrict__ w2u, const float* __restrict__ b2u,
                             float* __restrict__ out){
  __shared__ __align__(16) short sBuf[64 * SA_LD];
  __shared__ int sCnt[64];
  const int tid  = threadIdx.x;
  const int lane = tid & 63;
  const int wave = tid >> 6;
  const int q    = lane >> 4;
  const int lr   = lane & 15;
  const int n0   = blockIdx.x * 64;

  // Phase A: stage HsumB rows (bf16 copy, SA_LD stride) + sCnt
  {
    int row = tid >> 2;
    int qtr = tid & 3;
    int n = n0 + row; if (n >= N_NODES) n = 0;
    const short* hp = HsumB + (size_t)n * 256 + qtr * 64;
    short* dst = sBuf + row * SA_LD + qtr * 64;
    #pragma unroll
    for (int c = 0; c < 8; ++c){
      *(short8*)(dst + c * 8) = *(const short8*)(hp + c * 8);
    }
    if (tid < 64){
      int n2 = n0 + tid; if (n2 >= N_NODES) n2 = 0;
      sCnt[tid] = cnt[n2];
    }
  }
  __syncthreads();

  // Phase B: agg tile = Hsum @ W2m
  floatx4 agga[4][2];
  #pragma unroll
  for (int it = 0; it < 4; ++it){
    #pragma unroll
    for (int jt = 0; jt < 2; ++jt){
      #pragma unroll
      for (int r = 0; r < 4; ++r){ agga[it][jt][r] = 0.0f; }
    }
  }
  for (int kc = 0; kc < 8; ++kc){
    short8 aF[4];
    #pragma unroll
    for (int it = 0; it < 4; ++it){
      aF[it] = *(const short8*)(sBuf + (it * 16 + lr) * SA_LD + kc * 32 + q * 8);
    }
    #pragma unroll
    for (int jt = 0; jt < 2; ++jt){
      short8 bF = *(const short8*)(w2m + ((size_t)(kc * 8 + wave * 2 + jt) * 64 + lane) * 8);
      #pragma unroll
      for (int it = 0; it < 4; ++it){
        agga[it][jt] = __builtin_amdgcn_mfma_f32_16x16x32_bf16(aF[it], bF, agga[it][jt], 0, 0, 0);
      }
    }
  }
  __syncthreads();

  // Phase C: restage h (0..143) + pad (272..287) + agg tile (144..271)
  if (tid < 128){
    int row = tid >> 1;
    int half = tid & 1;
    int n = n0 + row; if (n >= N_NODES) n = 0;
    const short* srcp = h + (size_t)n * DF + half * 72;
    short* dstp = sBuf + row * SA_LD + half * 72;
    #pragma unroll
    for (int c = 0; c < 9; ++c){
      *(short8*)(dstp + c * 8) = *(const short8*)(srcp + c * 8);
    }
  } else {
    int t2 = tid - 128;
    int row = t2 >> 1;
    int half = t2 & 1;
    short* padp = sBuf + row * SA_LD + 272 + half * 8;
    #pragma unroll
    for (int t = 0; t < 8; ++t){ padp[t] = 0; }
  }
  #pragma unroll
  for (int jt = 0; jt < 2; ++jt){
    int colm = wave * 32 + jt * 16 + lr;
    int colb = 144 + wave * 32 + jt * 16 + (lr & ~1);
    float bb = b2m[colm];
    #pragma unroll
    for (int it = 0; it < 4; ++it){
      int rb = it * 16 + q * 4;
      float v0 = agga[it][jt][0] + (float)sCnt[rb + 0] * bb;
      float v1 = agga[it][jt][1] + (float)sCnt[rb + 1] * bb;
      float v2 = agga[it][jt][2] + (float)sCnt[rb + 2] * bb;
      float v3 = agga[it][jt][3] + (float)sCnt[rb + 3] * bb;
      unsigned int pk01 = pk_trunc(v0, v1);
      unsigned int pk23 = pk_trunc(v2, v3);
      unsigned int send = (lr & 1) ? pk01 : pk23;
      unsigned int t = (unsigned int)__shfl_xor((int)send, 1, 64);
      int row0;
      unsigned int w0, w1;
      if ((lr & 1) == 0){
        row0 = rb;
        w0 = (pk01 & 0xffffu) | ((t & 0xffffu) << 16);
        w1 = (pk01 >> 16)     | (t & 0xffff0000u);
      } else {
        row0 = rb + 2;
        w0 = (t & 0xffffu) | ((pk23 & 0xffffu) << 16);
        w1 = (t >> 16)     | (pk23 & 0xffff0000u);
      }
      *(unsigned int*)(sBuf + row0 * SA_LD + colb) = w0;
      *(unsigned int*)(sBuf + (row0 + 1) * SA_LD + colb) = w1;
    }
  }
  __syncthreads();

  // Phase D: layer 1 (K=288) -> relu -> SH_LD hidden
  floatx4 acc[4][4];
  #pragma unroll
  for (int it = 0; it < 4; ++it){
    #pragma unroll
    for (int jt = 0; jt < 4; ++jt){
      #pragma unroll
      for (int r = 0; r < 4; ++r){ acc[it][jt][r] = 0.0f; }
    }
  }
  for (int kc = 0; kc < 9; ++kc){
    short8 aF[4];
    #pragma unroll
    for (int it = 0; it < 4; ++it){
      aF[it] = *(const short8*)(sBuf + (it * 16 + lr) * SA_LD + kc * 32 + q * 8);
    }
    #pragma unroll
    for (int jt = 0; jt < 4; ++jt){
      short8 bF = *(const short8*)(w1u + ((size_t)(kc * 16 + wave * 4 + jt) * 64 + lane) * 8);
      #pragma unroll
      for (int it = 0; it < 4; ++it){
        acc[it][jt] = __builtin_amdgcn_mfma_f32_16x16x32_bf16(aF[it], bF, acc[it][jt], 0, 0, 0);
      }
    }
  }
  __syncthreads();
  #pragma unroll
  for (int jt = 0; jt < 4; ++jt){
    int col  = wave * 64 + jt * 16 + lr;
    int colb = wave * 64 + jt * 16 + (lr & ~1);
    float bb = b1u[col];
    #pragma unroll
    for (int it = 0; it < 4; ++it){
      floatx4 a = acc[it][jt];
      float v0 = a[0] + bb; v0 = v0 > 0.0f ? v0 : 0.0f;
      float v1 = a[1] + bb; v1 = v1 > 0.0f ? v1 : 0.0f;
      float v2 = a[2] + bb; v2 = v2 > 0.0f ? v2 : 0.0f;
      float v3 = a[3] + bb; v3 = v3 > 0.0f ? v3 : 0.0f;
      unsigned int pk01 = pk_trunc(v0, v1);
      unsigned int pk23 = pk_trunc(v2, v3);
      unsigned int send = (lr & 1) ? pk01 : pk23;
      unsigned int t = (unsigned int)__shfl_xor((int)send, 1, 64);
      int row0;
      unsigned int w0, w1;
      if ((lr & 1) == 0){
        row0 = it * 16 + q * 4;
        w0 = (pk01 & 0xffffu) | ((t & 0xffffu) << 16);
        w1 = (pk01 >> 16)     | (t & 0xffff0000u);
      } else {
        row0 = it * 16 + q * 4 + 2;
        w0 = (t & 0xffffu) | ((pk23 & 0xffffu) << 16);
        w1 = (t >> 16)     | (pk23 & 0xffff0000u);
      }
      *(unsigned int*)(sBuf + row0 * SH_LD + colb) = w0;
      *(unsigned int*)(sBuf + (row0 + 1) * SH_LD + colb) = w1;
    }
  }
  __syncthreads();

  // Phase E: layer 2 -> LDS-staged f32 -> coalesced out
  floatx4 acc2[4][2];
  #pragma unroll
  for (int it = 0; it < 4; ++it){
    #pragma unroll
    for (int jt = 0; jt < 2; ++jt){
      #pragma unroll
      for (int r = 0; r < 4; ++r){ acc2[it][jt][r] = 0.0f; }
    }
  }
  for (int kc = 0; kc < 8; ++kc){
    short8 aF[4];
    #pragma unroll
    for (int it = 0; it < 4; ++it){
      aF[it] = *(const short8*)(sBuf + (it * 16 + lr) * SH_LD + kc * 32 + q * 8);
    }
    #pragma unroll
    for (int jt = 0; jt < 2; ++jt){
      short8 bF = *(const short8*)(w2u + ((size_t)(kc * 8 + wave * 2 + jt) * 64 + lane) * 8);
      #pragma unroll
      for (int it = 0; it < 4; ++it){
        acc2[it][jt] = __builtin_amdgcn_mfma_f32_16x16x32_bf16(aF[it], bF, acc2[it][jt], 0, 0, 0);
      }
    }
  }
  __syncthreads();                      // done reading sBuf; reuse as f32 tile
  float* sO = (float*)sBuf;             // 64 rows x 132 f32 = 33792 B <= 37888 B
  #pragma unroll
  for (int jt = 0; jt < 2; ++jt){
    int col = wave * 32 + jt * 16 + lr;
    float bb = b2u[col];
    #pragma unroll
    for (int it = 0; it < 4; ++it){
      #pragma unroll
      for (int r = 0; r < 4; ++r){
        sO[(it * 16 + q * 4 + r) * 132 + col] = acc2[it][jt][r] + bb;
      }
    }
  }
  __syncthreads();
  #pragma unroll
  for (int rr = 0; rr < 8; ++rr){
    int row = rr * 8 + (tid >> 5);
    int n = n0 + row;
    if (n < N_NODES){
      *(floatx4*)(out + (size_t)n * DMSG + (tid & 31) * 4) =
          *(const floatx4*)(sO + row * 132 + (tid & 31) * 4);
    }
  }
}

extern "C" void kernel_launch(void* const* d_in, const int* in_sizes, int n_in,
                              void* d_out, int out_size, void* d_ws, size_t ws_size,
                              hipStream_t stream){
  const float* x   = (const float*)d_in[0];
  const int*   ei  = (const int*)d_in[1];
  const float* deg = (const float*)d_in[2];
  const float* mW1 = (const float*)d_in[3];
  const float* mb1 = (const float*)d_in[4];
  const float* mW2 = (const float*)d_in[5];
  const float* mb2 = (const float*)d_in[6];
  const float* uW1 = (const float*)d_in[7];
  const float* ub1 = (const float*)d_in[8];
  const float* uW2 = (const float*)d_in[9];
  const float* ub2 = (const float*)d_in[10];

  char* ws = (char*)d_ws;
  size_t off = 0;
  short* HsumB = (short*)(ws + off); off += (size_t)N_NODES * 256 * 2;   // 25.6 MB
  short* hbuf  = (short*)(ws + off); off += (size_t)N_NODES * DF * 2;    // 14.4 MB
  off = (off + 255) & ~(size_t)255;
  short* w2m  = (short*)(ws + off); off += (size_t)8 * 8 * 64 * 8 * 2;
  short* w1u  = (short*)(ws + off); off += (size_t)9 * 16 * 64 * 8 * 2;
  short* w2u  = (short*)(ws + off); off += (size_t)8 * 8 * 64 * 8 * 2;
  short* w1pq = (short*)(ws + off); off += (size_t)5 * 32 * 64 * 8 * 2;
  off = (off + 255) & ~(size_t)255;
  short* PQ = (short*)(ws + off); off += (size_t)N_NODES * PQ_LD * 2;    // 51.2 MB
  unsigned short* es = (unsigned short*)(ws + off); off += (size_t)N_NODES * ECAP * 2;  // 9.6 MB
  int* cnt   = (int*)(ws + off); off += (size_t)N_NODES * 4;             // 200 KB
  int* nOver = (int*)(ws + off); off += 256;
  unsigned int* over = (unsigned int*)(ws + off); off += (size_t)OVER_CAP * 4;
  // total ~101.5 MB; prior sessions proved ws_size >= ~121 MB, keep the guard

  if (ws_size < off){
    sentinel_kernel<<<(N_NODES * DMSG + 255) / 256, 256, 0, stream>>>((float*)d_out);
    return;
  }

  prep_pack_kernel<<<PREP_BLOCKS + PACK_BLOCKS, 256, 0, stream>>>(
      x, deg, mW1, mW2, uW1, uW2, w1pq, w2m, w1u, w2u, cnt, nOver, hbuf);
  pq_scatter_kernel<<<PQ_BLOCKS + HIST_BLOCKS, 256, 0, stream>>>(
      hbuf, w1pq, mb1, PQ, ei, cnt, nOver, over, es);
  hsum_kernel<<<(N_NODES + 3) / 4, 256, 0, stream>>>(PQ, es, cnt, over, nOver, HsumB);
  node2_kernel<<<(N_NODES + 63) / 64, 256, 0, stream>>>(hbuf, HsumB, cnt, w2m, mb2,
                                                        w1u, ub1, w2u, ub2,
                                                        (float*)d_out);
}

// Round 4
// 256.316 us; speedup vs baseline: 1.2898x; 1.0520x over previous
//
#include <hip/hip_runtime.h>

// MPNN sparse on MI355X (fp32 I/O, bf16 MFMA compute).
// R12 (resubmit — R12 bench was lost to GPUAcquisitionTimeout, no data).
// Depth-4 pipelined gather in hsum.
//   R11 post-mortem (269.6us, prediction matched): pack_hist/scans deleted,
//   pq_scatter off the top-5. New #1 = hsum 72us: FETCH 189MB @ 2.6TB/s (38%),
//   VALU 35%, 0 bank conflicts -> nothing saturated = latency-bound gather.
//   The j-loop kept ONE outstanding Q-row load per wave (single qn prefetch)
//   against ~400cy random-access latency.
// Fix: software-pipeline the Q gather 4-deep with statically-named regs
//   q0..q3 (runtime-indexed reg arrays spill to scratch). Prefetch indices
//   past m clamp to lanes holding source 0 -> valid discarded loads, no
//   per-load guards; accumulate guards are wave-uniform. +~12 VGPR on a
//   20-VGPR kernel.
// Pipeline (4 kernels): prep+pack -> pq_gemm|scatter -> hsum -> node2.

#define N_NODES 50000
#define E_EDGES 800000
#define DF   144
#define DIN  128
#define DDEG 16
#define DMSG 128
#define SA_LD 296     // 288 + 8 pad (shorts)
#define SH_LD 264     // 256 + 8 pad (shorts)
#define PQ_LD 512     // P'(256) | Q(256) per node, bf16
#define KA_LD 168     // 160 + 8 pad (pq A staging)
#define EP_W  68      // epilogue LDS stride in words (64 data + 4 pad)
#define ECAP 96       // fixed bucket capacity per target
#define OVER_CAP 4096
#define PQ_BLOCKS 782     // ceil(50000/64)
#define HIST_BLOCKS 3125  // 800000/256
#define PACK_THREADS 27648
#define PREP_BLOCKS 3516  // ceil(50000*18/256)
#define PACK_BLOCKS 108   // 27648/256

typedef __attribute__((ext_vector_type(8))) short short8;
typedef __attribute__((ext_vector_type(4))) float floatx4;
typedef __attribute__((ext_vector_type(4))) unsigned int uintx4;

__device__ __forceinline__ unsigned int fasu(float f){
  union { float f; unsigned int u; } v; v.f = f; return v.u;
}
__device__ __forceinline__ float uasf(unsigned int u){
  union { unsigned int u; float f; } v; v.u = u; return v.f;
}
__device__ __forceinline__ short f2bf(float f){           // RNE
  unsigned int i = fasu(f);
  unsigned int r = i + 0x7fffu + ((i >> 16) & 1u);
  return (short)(r >> 16);
}
__device__ __forceinline__ unsigned int pk_trunc(float lo, float hi){
  return __builtin_amdgcn_perm(fasu(hi), fasu(lo), 0x07060302u);
}

// ---- sentinel: ws too small -> out = 2.0 (diagnostic) ----
__global__ void sentinel_kernel(float* __restrict__ out){
  int i = blockIdx.x * blockDim.x + threadIdx.x;
  if (i < N_NODES * DMSG){ out[i] = 2.0f; }
}

// ---- pack helpers ----
__device__ __forceinline__ void pack_w_dev(const float* __restrict__ W,
                                           short* __restrict__ Wp,
                                           int Ksrc, int nT, int t){
  int lane = t & 63;
  int rest = t >> 6;
  int nt = rest % nT;
  int chunk = rest / nT;
  int Ncols = nT * 16;
  int n = nt * 16 + (lane & 15);
  int kbase = chunk * 32 + (lane >> 4) * 8;
  short8 v;
  for (int j = 0; j < 8; ++j){
    int k = kbase + j;
    short o = 0;
    if (k < Ksrc){ o = f2bf(W[(size_t)k * Ncols + n]); }
    v[j] = o;
  }
  *(short8*)(Wp + (size_t)t * 8) = v;
}
__device__ __forceinline__ void pack_w1pq_dev(const float* __restrict__ W1,
                                              short* __restrict__ Wp, int t){
  int lane = t & 63;
  int rest = t >> 6;
  int nt = rest % 32;
  int chunk = rest / 32;
  int col = nt * 16 + (lane & 15);
  int kbase = chunk * 32 + (lane >> 4) * 8;
  short8 v;
  for (int j = 0; j < 8; ++j){
    int k = kbase + j;
    short o = 0;
    if (k < 144){
      float w = (col < 256) ? W1[(size_t)k * 256 + col]
                            : W1[(size_t)(144 + k) * 256 + (col - 256)];
      o = f2bf(w);
    }
    v[j] = o;
  }
  *(short8*)(Wp + (size_t)t * 8) = v;
}

// ---- kernel 1: prep (cnt=0, nOver=0, h=bf16[x|deg]) + weight pack ----
__global__ void prep_pack_kernel(const float* __restrict__ x, const float* __restrict__ deg,
                                 const float* __restrict__ mW1, const float* __restrict__ mW2,
                                 const float* __restrict__ uW1, const float* __restrict__ uW2,
                                 short* __restrict__ w1pq, short* __restrict__ w2m,
                                 short* __restrict__ w1u, short* __restrict__ w2u,
                                 int* __restrict__ cnt, int* __restrict__ nOver,
                                 short* __restrict__ h){
  if (blockIdx.x >= PREP_BLOCKS){
    int t2 = (blockIdx.x - PREP_BLOCKS) * 256 + threadIdx.x;
    if (t2 < 4096){ pack_w_dev(mW2, w2m, 256, 8, t2); }
    else if (t2 < 13312){ pack_w_dev(uW1, w1u, 272, 16, t2 - 4096); }
    else if (t2 < 17408){ pack_w_dev(uW2, w2u, 256, 8, t2 - 13312); }
    else { pack_w1pq_dev(mW1, w1pq, t2 - 17408); }
    return;
  }
  int i = blockIdx.x * 256 + threadIdx.x;
  if (i < N_NODES){ cnt[i] = 0; }
  if (i == 0){ *nOver = 0; }
  if (i < N_NODES * 18){
    int n = i / 18;
    int j = i - n * 18;
    const float* src;
    if (j < 16){ src = x + (size_t)n * DIN + (size_t)j * 8; }
    else       { src = deg + (size_t)n * DDEG + (size_t)(j - 16) * 8; }
    short8 v;
    for (int t = 0; t < 8; ++t){ v[t] = f2bf(src[t]); }
    *(short8*)(h + (size_t)n * DF + (size_t)j * 8) = v;
  }
}

// ---- kernel 2: fused PQ GEMM + single-pass edge scatter (interleaved) ----
__launch_bounds__(256, 2)
__global__ void pq_scatter_kernel(const short* __restrict__ h, const short* __restrict__ w1pq,
                                  const float* __restrict__ b1, short* __restrict__ PQ,
                                  const int* __restrict__ ei, int* __restrict__ cnt,
                                  int* __restrict__ nOver, unsigned int* __restrict__ over,
                                  unsigned short* __restrict__ es){
  __shared__ __align__(16) unsigned int sE[4 * 32 * EP_W];   // 34816 B, unioned with sA

  const int g = blockIdx.x;
  const bool isG = ((g % 5) == 0) && ((g / 5) < PQ_BLOCKS);
  if (!isG){
    // scatter block: one atomic per edge = rank AND histogram
    int nb = (g / 5) + 1; if (nb > PQ_BLOCKS) nb = PQ_BLOCKS;
    int e = (g - nb) * 256 + threadIdx.x;
    if (e < E_EDGES){
      int s = ei[e];
      int t = ei[E_EDGES + e];
      if ((unsigned)s >= (unsigned)N_NODES) s = 0;
      if ((unsigned)t >= (unsigned)N_NODES) t = 0;
      int r = atomicAdd(cnt + t, 1);
      if (r < ECAP){
        es[(size_t)t * ECAP + r] = (unsigned short)s;
      } else {
        int p = atomicAdd(nOver, 1);
        if (p < OVER_CAP){ over[p] = ((unsigned int)t << 16) | (unsigned int)s; }
      }
    }
    return;
  }

  const int tid  = threadIdx.x;
  const int lane = tid & 63;
  const int wave = tid >> 6;
  const int q    = lane >> 4;
  const int lr   = lane & 15;
  const int n0   = (g / 5) * 64;
  short* sA = (short*)sE;

  {
    int row = tid >> 2;
    int quarter = tid & 3;
    int n = n0 + row;
    if (n >= N_NODES) n = 0;
    const short* hp = h + (size_t)n * DF;
    short* dstp = sA + row * KA_LD + quarter * 40;
    #pragma unroll
    for (int c5 = 0; c5 < 5; ++c5){
      int col = quarter * 40 + c5 * 8;
      short8 v;
      if (col < DF){
        v = *(const short8*)(hp + col);
      } else {
        for (int j = 0; j < 8; ++j){ v[j] = 0; }
      }
      *(short8*)(dstp + c5 * 8) = v;
    }
  }
  __syncthreads();

  floatx4 acc[4][8];
  #pragma unroll
  for (int it = 0; it < 4; ++it){
    #pragma unroll
    for (int jt = 0; jt < 8; ++jt){
      #pragma unroll
      for (int r = 0; r < 4; ++r){ acc[it][jt][r] = 0.0f; }
    }
  }

  for (int kc = 0; kc < 5; ++kc){
    short8 aF[4];
    #pragma unroll
    for (int it = 0; it < 4; ++it){
      aF[it] = *(const short8*)(sA + (it * 16 + lr) * KA_LD + kc * 32 + q * 8);
    }
    #pragma unroll
    for (int jt = 0; jt < 8; ++jt){
      short8 bF = *(const short8*)(w1pq + ((size_t)(kc * 32 + wave * 8 + jt) * 64 + lane) * 8);
      #pragma unroll
      for (int it = 0; it < 4; ++it){
        acc[it][jt] = __builtin_amdgcn_mfma_f32_16x16x32_bf16(aF[it], bF, acc[it][jt], 0, 0, 0);
      }
    }
  }
  __syncthreads();   // all waves done reading sA before epilogue overwrites it

  // Epilogue: wave-private LDS staging (2 rounds x 32 rows), coalesced PQ rows.
  const int waveBase = wave * (32 * EP_W);
  #pragma unroll
  for (int rnd = 0; rnd < 2; ++rnd){
    #pragma unroll
    for (int il = 0; il < 2; ++il){
      const int it = rnd * 2 + il;
      #pragma unroll
      for (int jt = 0; jt < 8; ++jt){
        int col  = (wave * 8 + jt) * 16 + lr;
        float bb = (col < 256) ? b1[col] : 0.0f;
        floatx4 a = acc[it][jt];
        unsigned int pk01 = pk_trunc(a[0] + bb, a[1] + bb);
        unsigned int pk23 = pk_trunc(a[2] + bb, a[3] + bb);
        unsigned int send = (lr & 1) ? pk01 : pk23;
        unsigned int t = (unsigned int)__shfl_xor((int)send, 1, 64);
        int lrow;
        unsigned int w0, w1;
        if ((lr & 1) == 0){
          lrow = il * 16 + q * 4;
          w0 = (pk01 & 0xffffu) | ((t & 0xffffu) << 16);
          w1 = (pk01 >> 16)     | (t & 0xffff0000u);
        } else {
          lrow = il * 16 + q * 4 + 2;
          w0 = (t & 0xffffu) | ((pk23 & 0xffffu) << 16);
          w1 = (t >> 16)     | (pk23 & 0xffff0000u);
        }
        int wv = jt * 8 + (lr >> 1);
        sE[waveBase + lrow * EP_W + wv] = w0;
        sE[waveBase + (lrow + 1) * EP_W + wv] = w1;
      }
    }
    #pragma unroll
    for (int rr = 0; rr < 8; ++rr){
      int lrow = rr * 4 + (lane >> 4);
      int grow = n0 + rnd * 32 + lrow;
      uintx4 v = *(const uintx4*)(sE + waveBase + lrow * EP_W + (lane & 15) * 4);
      if (grow < N_NODES){
        *(uintx4*)((unsigned int*)PQ + (size_t)grow * 256 + wave * 64 + (lane & 15) * 4) = v;
      }
    }
  }
}

// ---- kernel 3: hsum — one wave per target; depth-4 pipelined gather ----
__launch_bounds__(256, 8)
__global__ void hsum_kernel(const short* __restrict__ PQ, const unsigned short* __restrict__ es,
                            const int* __restrict__ cnt, const unsigned int* __restrict__ over,
                            const int* __restrict__ nOver, short* __restrict__ HsumB){
  const int lane = threadIdx.x & 63;
  const int wave = threadIdx.x >> 6;
  const int t = blockIdx.x * 4 + wave;          // grid covers exactly N_NODES
  const unsigned int* PQu = (const unsigned int*)PQ;

  float a0 = 0.0f, a1 = 0.0f, a2 = 0.0f, a3 = 0.0f;
  int d = cnt[t];
  if (d > 0){
    int dc = d < ECAP ? d : ECAP;
    int start = t * ECAP;
    uint2 pv = *(const uint2*)(PQu + (size_t)t * 256 + lane * 2);
    float Pf0 = uasf(pv.x << 16), Pf1 = uasf(pv.x & 0xffff0000u);
    float Pf2 = uasf(pv.y << 16), Pf3 = uasf(pv.y & 0xffff0000u);

    // Q-row pull by wave-uniform lane index; indices past m hit lanes with
    // el=0 -> source 0 -> valid discarded load (no per-load guard needed).
    #define LDQ(idx) (*(const uint2*)(PQu + (size_t)(unsigned int)__shfl((int)el, (idx), 64) * 256 + 128 + lane * 2))
    #define ACCQ(qv) { float v;                                        \
        v = Pf0 + uasf((qv).x << 16);          a0 += v > 0.0f ? v : 0.0f; \
        v = Pf1 + uasf((qv).x & 0xffff0000u);  a1 += v > 0.0f ? v : 0.0f; \
        v = Pf2 + uasf((qv).y << 16);          a2 += v > 0.0f ? v : 0.0f; \
        v = Pf3 + uasf((qv).y & 0xffff0000u);  a3 += v > 0.0f ? v : 0.0f; }

    for (int base = 0; base < dc; base += 64){
      int m = dc - base;
      if (m > 64) m = 64;
      unsigned int el = (lane < m) ? (unsigned int)es[start + base + lane] : 0u;
      // depth-4 software pipeline with statically-named regs (no scratch)
      uint2 q0 = LDQ(0);
      uint2 q1 = LDQ(1);
      uint2 q2 = LDQ(2);
      uint2 q3 = LDQ(3);
      for (int j = 0; j < m; j += 4){
        uint2 t0 = q0, t1 = q1, t2 = q2, t3 = q3;
        int i0 = j + 4, i1 = j + 5, i2 = j + 6, i3 = j + 7;
        q0 = LDQ(i0 < 64 ? i0 : 0);
        q1 = LDQ(i1 < 64 ? i1 : 0);
        q2 = LDQ(i2 < 64 ? i2 : 0);
        q3 = LDQ(i3 < 64 ? i3 : 0);
        ACCQ(t0);
        if (j + 1 < m){ ACCQ(t1); }
        if (j + 2 < m){ ACCQ(t2); }
        if (j + 3 < m){ ACCQ(t3); }
      }
    }
    #undef LDQ
    #undef ACCQ

    if (d > ECAP){   // astronomically rare; guaranteed-correct replay
      int no = *nOver;
      if (no > OVER_CAP) no = OVER_CAP;
      for (int p = 0; p < no; ++p){
        unsigned int w = over[p];
        if ((int)(w >> 16) == t){
          unsigned int s1 = w & 0xffffu;
          uint2 qv = *(const uint2*)(PQu + (size_t)s1 * 256 + 128 + lane * 2);
          float v;
          v = Pf0 + uasf(qv.x << 16);          a0 += v > 0.0f ? v : 0.0f;
          v = Pf1 + uasf(qv.x & 0xffff0000u);  a1 += v > 0.0f ? v : 0.0f;
          v = Pf2 + uasf(qv.y << 16);          a2 += v > 0.0f ? v : 0.0f;
          v = Pf3 + uasf(qv.y & 0xffff0000u);  a3 += v > 0.0f ? v : 0.0f;
        }
      }
    }
  }
  uint2 o;
  o.x = pk_trunc(a0, a1);
  o.y = pk_trunc(a2, a3);
  *(uint2*)((unsigned int*)HsumB + (size_t)t * 128 + lane * 2) = o;
}

// ---- kernel 4: node2 — agg = HsumB@W2m + cnt*b2m fused in front of node MLP ----
__launch_bounds__(256, 4)
__global__ void node2_kernel(const short* __restrict__ h, const short* __restrict__ HsumB,
                             const int* __restrict__ cnt,
                             const short* __restrict__ w2m, const float* __restrict__ b2m,
                             const short* __restrict__ w1u, const float* __restrict__ b1u,
                             const short* __restrict__ w2u, const float* __restrict__ b2u,
                             float* __restrict__ out){
  __shared__ __align__(16) short sBuf[64 * SA_LD];
  __shared__ int sCnt[64];
  const int tid  = threadIdx.x;
  const int lane = tid & 63;
  const int wave = tid >> 6;
  const int q    = lane >> 4;
  const int lr   = lane & 15;
  const int n0   = blockIdx.x * 64;

  // Phase A: stage HsumB rows (bf16 copy, SA_LD stride) + sCnt
  {
    int row = tid >> 2;
    int qtr = tid & 3;
    int n = n0 + row; if (n >= N_NODES) n = 0;
    const short* hp = HsumB + (size_t)n * 256 + qtr * 64;
    short* dst = sBuf + row * SA_LD + qtr * 64;
    #pragma unroll
    for (int c = 0; c < 8; ++c){
      *(short8*)(dst + c * 8) = *(const short8*)(hp + c * 8);
    }
    if (tid < 64){
      int n2 = n0 + tid; if (n2 >= N_NODES) n2 = 0;
      sCnt[tid] = cnt[n2];
    }
  }
  __syncthreads();

  // Phase B: agg tile = Hsum @ W2m
  floatx4 agga[4][2];
  #pragma unroll
  for (int it = 0; it < 4; ++it){
    #pragma unroll
    for (int jt = 0; jt < 2; ++jt){
      #pragma unroll
      for (int r = 0; r < 4; ++r){ agga[it][jt][r] = 0.0f; }
    }
  }
  for (int kc = 0; kc < 8; ++kc){
    short8 aF[4];
    #pragma unroll
    for (int it = 0; it < 4; ++it){
      aF[it] = *(const short8*)(sBuf + (it * 16 + lr) * SA_LD + kc * 32 + q * 8);
    }
    #pragma unroll
    for (int jt = 0; jt < 2; ++jt){
      short8 bF = *(const short8*)(w2m + ((size_t)(kc * 8 + wave * 2 + jt) * 64 + lane) * 8);
      #pragma unroll
      for (int it = 0; it < 4; ++it){
        agga[it][jt] = __builtin_amdgcn_mfma_f32_16x16x32_bf16(aF[it], bF, agga[it][jt], 0, 0, 0);
      }
    }
  }
  __syncthreads();

  // Phase C: restage h (0..143) + pad (272..287) + agg tile (144..271)
  if (tid < 128){
    int row = tid >> 1;
    int half = tid & 1;
    int n = n0 + row; if (n >= N_NODES) n = 0;
    const short* srcp = h + (size_t)n * DF + half * 72;
    short* dstp = sBuf + row * SA_LD + half * 72;
    #pragma unroll
    for (int c = 0; c < 9; ++c){
      *(short8*)(dstp + c * 8) = *(const short8*)(srcp + c * 8);
    }
  } else {
    int t2 = tid - 128;
    int row = t2 >> 1;
    int half = t2 & 1;
    short* padp = sBuf + row * SA_LD + 272 + half * 8;
    #pragma unroll
    for (int t = 0; t < 8; ++t){ padp[t] = 0; }
  }
  #pragma unroll
  for (int jt = 0; jt < 2; ++jt){
    int colm = wave * 32 + jt * 16 + lr;
    int colb = 144 + wave * 32 + jt * 16 + (lr & ~1);
    float bb = b2m[colm];
    #pragma unroll
    for (int it = 0; it < 4; ++it){
      int rb = it * 16 + q * 4;
      float v0 = agga[it][jt][0] + (float)sCnt[rb + 0] * bb;
      float v1 = agga[it][jt][1] + (float)sCnt[rb + 1] * bb;
      float v2 = agga[it][jt][2] + (float)sCnt[rb + 2] * bb;
      float v3 = agga[it][jt][3] + (float)sCnt[rb + 3] * bb;
      unsigned int pk01 = pk_trunc(v0, v1);
      unsigned int pk23 = pk_trunc(v2, v3);
      unsigned int send = (lr & 1) ? pk01 : pk23;
      unsigned int t = (unsigned int)__shfl_xor((int)send, 1, 64);
      int row0;
      unsigned int w0, w1;
      if ((lr & 1) == 0){
        row0 = rb;
        w0 = (pk01 & 0xffffu) | ((t & 0xffffu) << 16);
        w1 = (pk01 >> 16)     | (t & 0xffff0000u);
      } else {
        row0 = rb + 2;
        w0 = (t & 0xffffu) | ((pk23 & 0xffffu) << 16);
        w1 = (t >> 16)     | (pk23 & 0xffff0000u);
      }
      *(unsigned int*)(sBuf + row0 * SA_LD + colb) = w0;
      *(unsigned int*)(sBuf + (row0 + 1) * SA_LD + colb) = w1;
    }
  }
  __syncthreads();

  // Phase D: layer 1 (K=288) -> relu -> SH_LD hidden
  floatx4 acc[4][4];
  #pragma unroll
  for (int it = 0; it < 4; ++it){
    #pragma unroll
    for (int jt = 0; jt < 4; ++jt){
      #pragma unroll
      for (int r = 0; r < 4; ++r){ acc[it][jt][r] = 0.0f; }
    }
  }
  for (int kc = 0; kc < 9; ++kc){
    short8 aF[4];
    #pragma unroll
    for (int it = 0; it < 4; ++it){
      aF[it] = *(const short8*)(sBuf + (it * 16 + lr) * SA_LD + kc * 32 + q * 8);
    }
    #pragma unroll
    for (int jt = 0; jt < 4; ++jt){
      short8 bF = *(const short8*)(w1u + ((size_t)(kc * 16 + wave * 4 + jt) * 64 + lane) * 8);
      #pragma unroll
      for (int it = 0; it < 4; ++it){
        acc[it][jt] = __builtin_amdgcn_mfma_f32_16x16x32_bf16(aF[it], bF, acc[it][jt], 0, 0, 0);
      }
    }
  }
  __syncthreads();
  #pragma unroll
  for (int jt = 0; jt < 4; ++jt){
    int col  = wave * 64 + jt * 16 + lr;
    int colb = wave * 64 + jt * 16 + (lr & ~1);
    float bb = b1u[col];
    #pragma unroll
    for (int it = 0; it < 4; ++it){
      floatx4 a = acc[it][jt];
      float v0 = a[0] + bb; v0 = v0 > 0.0f ? v0 : 0.0f;
      float v1 = a[1] + bb; v1 = v1 > 0.0f ? v1 : 0.0f;
      float v2 = a[2] + bb; v2 = v2 > 0.0f ? v2 : 0.0f;
      float v3 = a[3] + bb; v3 = v3 > 0.0f ? v3 : 0.0f;
      unsigned int pk01 = pk_trunc(v0, v1);
      unsigned int pk23 = pk_trunc(v2, v3);
      unsigned int send = (lr & 1) ? pk01 : pk23;
      unsigned int t = (unsigned int)__shfl_xor((int)send, 1, 64);
      int row0;
      unsigned int w0, w1;
      if ((lr & 1) == 0){
        row0 = it * 16 + q * 4;
        w0 = (pk01 & 0xffffu) | ((t & 0xffffu) << 16);
        w1 = (pk01 >> 16)     | (t & 0xffff0000u);
      } else {
        row0 = it * 16 + q * 4 + 2;
        w0 = (t & 0xffffu) | ((pk23 & 0xffffu) << 16);
        w1 = (t >> 16)     | (pk23 & 0xffff0000u);
      }
      *(unsigned int*)(sBuf + row0 * SH_LD + colb) = w0;
      *(unsigned int*)(sBuf + (row0 + 1) * SH_LD + colb) = w1;
    }
  }
  __syncthreads();

  // Phase E: layer 2 -> LDS-staged f32 -> coalesced out
  floatx4 acc2[4][2];
  #pragma unroll
  for (int it = 0; it < 4; ++it){
    #pragma unroll
    for (int jt = 0; jt < 2; ++jt){
      #pragma unroll
      for (int r = 0; r < 4; ++r){ acc2[it][jt][r] = 0.0f; }
    }
  }
  for (int kc = 0; kc < 8; ++kc){
    short8 aF[4];
    #pragma unroll
    for (int it = 0; it < 4; ++it){
      aF[it] = *(const short8*)(sBuf + (it * 16 + lr) * SH_LD + kc * 32 + q * 8);
    }
    #pragma unroll
    for (int jt = 0; jt < 2; ++jt){
      short8 bF = *(const short8*)(w2u + ((size_t)(kc * 8 + wave * 2 + jt) * 64 + lane) * 8);
      #pragma unroll
      for (int it = 0; it < 4; ++it){
        acc2[it][jt] = __builtin_amdgcn_mfma_f32_16x16x32_bf16(aF[it], bF, acc2[it][jt], 0, 0, 0);
      }
    }
  }
  __syncthreads();                      // done reading sBuf; reuse as f32 tile
  float* sO = (float*)sBuf;             // 64 rows x 132 f32 = 33792 B <= 37888 B
  #pragma unroll
  for (int jt = 0; jt < 2; ++jt){
    int col = wave * 32 + jt * 16 + lr;
    float bb = b2u[col];
    #pragma unroll
    for (int it = 0; it < 4; ++it){
      #pragma unroll
      for (int r = 0; r < 4; ++r){
        sO[(it * 16 + q * 4 + r) * 132 + col] = acc2[it][jt][r] + bb;
      }
    }
  }
  __syncthreads();
  #pragma unroll
  for (int rr = 0; rr < 8; ++rr){
    int row = rr * 8 + (tid >> 5);
    int n = n0 + row;
    if (n < N_NODES){
      *(floatx4*)(out + (size_t)n * DMSG + (tid & 31) * 4) =
          *(const floatx4*)(sO + row * 132 + (tid & 31) * 4);
    }
  }
}

extern "C" void kernel_launch(void* const* d_in, const int* in_sizes, int n_in,
                              void* d_out, int out_size, void* d_ws, size_t ws_size,
                              hipStream_t stream){
  const float* x   = (const float*)d_in[0];
  const int*   ei  = (const int*)d_in[1];
  const float* deg = (const float*)d_in[2];
  const float* mW1 = (const float*)d_in[3];
  const float* mb1 = (const float*)d_in[4];
  const float* mW2 = (const float*)d_in[5];
  const float* mb2 = (const float*)d_in[6];
  const float* uW1 = (const float*)d_in[7];
  const float* ub1 = (const float*)d_in[8];
  const float* uW2 = (const float*)d_in[9];
  const float* ub2 = (const float*)d_in[10];

  char* ws = (char*)d_ws;
  size_t off = 0;
  short* HsumB = (short*)(ws + off); off += (size_t)N_NODES * 256 * 2;   // 25.6 MB
  short* hbuf  = (short*)(ws + off); off += (size_t)N_NODES * DF * 2;    // 14.4 MB
  off = (off + 255) & ~(size_t)255;
  short* w2m  = (short*)(ws + off); off += (size_t)8 * 8 * 64 * 8 * 2;
  short* w1u  = (short*)(ws + off); off += (size_t)9 * 16 * 64 * 8 * 2;
  short* w2u  = (short*)(ws + off); off += (size_t)8 * 8 * 64 * 8 * 2;
  short* w1pq = (short*)(ws + off); off += (size_t)5 * 32 * 64 * 8 * 2;
  off = (off + 255) & ~(size_t)255;
  short* PQ = (short*)(ws + off); off += (size_t)N_NODES * PQ_LD * 2;    // 51.2 MB
  unsigned short* es = (unsigned short*)(ws + off); off += (size_t)N_NODES * ECAP * 2;  // 9.6 MB
  int* cnt   = (int*)(ws + off); off += (size_t)N_NODES * 4;             // 200 KB
  int* nOver = (int*)(ws + off); off += 256;
  unsigned int* over = (unsigned int*)(ws + off); off += (size_t)OVER_CAP * 4;
  // total ~101.5 MB; prior sessions proved ws_size >= ~121 MB, keep the guard

  if (ws_size < off){
    sentinel_kernel<<<(N_NODES * DMSG + 255) / 256, 256, 0, stream>>>((float*)d_out);
    return;
  }

  prep_pack_kernel<<<PREP_BLOCKS + PACK_BLOCKS, 256, 0, stream>>>(
      x, deg, mW1, mW2, uW1, uW2, w1pq, w2m, w1u, w2u, cnt, nOver, hbuf);
  pq_scatter_kernel<<<PQ_BLOCKS + HIST_BLOCKS, 256, 0, stream>>>(
      hbuf, w1pq, mb1, PQ, ei, cnt, nOver, over, es);
  hsum_kernel<<<(N_NODES + 3) / 4, 256, 0, stream>>>(PQ, es, cnt, over, nOver, HsumB);
  node2_kernel<<<(N_NODES + 63) / 64, 256, 0, stream>>>(hbuf, HsumB, cnt, w2m, mb2,
                                                        w1u, ub1, w2u, ub2,
                                                        (float*)d_out);
}